// Round 1
// baseline (229.882 us; speedup 1.0000x reference)
//
#include <hip/hip_runtime.h>
#include <cmath>

namespace {

constexpr float kNegInf = -1000000000.0f;
constexpr float kSlope  = 0.2f;

// Per-block scratch: 145,664 B = 142.25 KiB  (gfx950 LDS = 160 KiB/CU)
struct alignas(16) SMem {
  float Wh[128][132];        // Wh = h@W + b   (padded stride)
  float A_T[128][128];       // attention, transposed: A_T[j][i] = A[i][j]
  float hsT[8][132];         // h chunk, k-major
  float Ws[8][132];          // W chunk
  float f1[128];
  float f2[128];
  float mrow[128];
  float linv[128];
  unsigned int adj[128][4];  // bit-packed adjacency rows
};

__device__ __forceinline__ float leaky(float x) {
  return x >= 0.0f ? x : kSlope * x;
}

__global__ __launch_bounds__(256, 1) void gat_fused(
    const float* __restrict__ h,    // [BS][128][128]
    const float* __restrict__ Ww,   // [128][128]
    const float* __restrict__ Wb,   // [128]
    const float* __restrict__ a1v,  // [128]
    const float* __restrict__ a2v,  // [128]
    const float* __restrict__ abp,  // [1]
    const int*   __restrict__ adj,  // [128][128]
    float* __restrict__ out) {      // [BS][128][128]
  __shared__ SMem sm;
  const int t  = threadIdx.x;
  const int bs = blockIdx.x;
  const int ty = t >> 4;       // 0..15
  const int tx = t & 15;       // 0..15
  const int i0 = ty << 3;      // row base of this thread's 8x8 tile
  const int g0 = tx << 3;      // col base

  const float ab = abp[0];

  // Per-thread column fragments of a1/a2/Wb (global, L2-resident)
  float a1c[8], a2c[8], wbc[8];
  {
    float4 v;
    v = *(const float4*)(a1v + g0);     a1c[0]=v.x; a1c[1]=v.y; a1c[2]=v.z; a1c[3]=v.w;
    v = *(const float4*)(a1v + g0 + 4); a1c[4]=v.x; a1c[5]=v.y; a1c[6]=v.z; a1c[7]=v.w;
    v = *(const float4*)(a2v + g0);     a2c[0]=v.x; a2c[1]=v.y; a2c[2]=v.z; a2c[3]=v.w;
    v = *(const float4*)(a2v + g0 + 4); a2c[4]=v.x; a2c[5]=v.y; a2c[6]=v.z; a2c[7]=v.w;
    v = *(const float4*)(Wb  + g0);     wbc[0]=v.x; wbc[1]=v.y; wbc[2]=v.z; wbc[3]=v.w;
    v = *(const float4*)(Wb  + g0 + 4); wbc[4]=v.x; wbc[5]=v.y; wbc[6]=v.z; wbc[7]=v.w;
  }

  // Stage adjacency as bitmasks: thread t packs 2 of the 512 words
  {
    const int row = t >> 1;
    const int wbase = (t & 1) << 1;
#pragma unroll
    for (int w = 0; w < 2; ++w) {
      const int* ap = adj + row * 128 + ((wbase + w) << 5);
      unsigned int bits = 0u;
#pragma unroll
      for (int b = 0; b < 32; ++b) bits |= (ap[b] != 0 ? (1u << b) : 0u);
      sm.adj[row][wbase + w] = bits;
    }
  }

  // ---------------- matmul1: Wh = h @ W ----------------
  float acc[8][8];
#pragma unroll
  for (int r = 0; r < 8; ++r)
#pragma unroll
    for (int c = 0; c < 8; ++c) acc[r][c] = 0.0f;

  const float* hblk = h + (size_t)bs * (128 * 128);

  for (int kt = 0; kt < 16; ++kt) {
    __syncthreads();  // staging buffers free (also orders adj writes on kt=0)
    {  // stage W[kt*8 .. +7][:]  (coalesced float4)
      const int kk = t >> 5;
      const int gq = (t & 31) << 2;
      *(float4*)(&sm.Ws[kk][gq]) = *(const float4*)(Ww + (kt * 8 + kk) * 128 + gq);
    }
    {  // stage h[:, kt*8 .. +7] transposed to k-major
      const int i = t >> 1;
      const int c = (t & 1) << 2;
      float4 v = *(const float4*)(hblk + i * 128 + kt * 8 + c);
      sm.hsT[c + 0][i] = v.x;
      sm.hsT[c + 1][i] = v.y;
      sm.hsT[c + 2][i] = v.z;
      sm.hsT[c + 3][i] = v.w;
    }
    __syncthreads();
#pragma unroll
    for (int kk = 0; kk < 8; ++kk) {
      float af[8], bf[8];
      {
        float4 v;
        v = *(const float4*)(&sm.hsT[kk][i0]);     af[0]=v.x; af[1]=v.y; af[2]=v.z; af[3]=v.w;
        v = *(const float4*)(&sm.hsT[kk][i0 + 4]); af[4]=v.x; af[5]=v.y; af[6]=v.z; af[7]=v.w;
        v = *(const float4*)(&sm.Ws[kk][g0]);      bf[0]=v.x; bf[1]=v.y; bf[2]=v.z; bf[3]=v.w;
        v = *(const float4*)(&sm.Ws[kk][g0 + 4]);  bf[4]=v.x; bf[5]=v.y; bf[6]=v.z; bf[7]=v.w;
      }
#pragma unroll
      for (int r = 0; r < 8; ++r)
#pragma unroll
        for (int c = 0; c < 8; ++c) acc[r][c] = fmaf(af[r], bf[c], acc[r][c]);
    }
  }

  // ---- bias, f1/f2 (register-side dot + 16-lane shuffle reduce), Wh -> LDS ----
#pragma unroll
  for (int r = 0; r < 8; ++r) {
    float s1 = 0.0f, s2 = 0.0f;
#pragma unroll
    for (int c = 0; c < 8; ++c) {
      acc[r][c] += wbc[c];
      s1 = fmaf(acc[r][c], a1c[c], s1);
      s2 = fmaf(acc[r][c], a2c[c], s2);
    }
#pragma unroll
    for (int off = 8; off >= 1; off >>= 1) {
      s1 += __shfl_xor(s1, off, 16);
      s2 += __shfl_xor(s2, off, 16);
    }
    if (tx == 0) {
      sm.f1[i0 + r] = s1;
      sm.f2[i0 + r] = s2;
    }
    float4 lo = make_float4(acc[r][0], acc[r][1], acc[r][2], acc[r][3]);
    float4 hi = make_float4(acc[r][4], acc[r][5], acc[r][6], acc[r][7]);
    *(float4*)(&sm.Wh[i0 + r][g0])     = lo;
    *(float4*)(&sm.Wh[i0 + r][g0 + 4]) = hi;
  }
  __syncthreads();

  // ---------------- softmax stats: one row per thread (threads 0..127) ----------------
  if (t < 128) {
    const float f1i = sm.f1[t] + ab;
    float m = kNegInf;
#pragma unroll
    for (int w = 0; w < 4; ++w) {
      const unsigned int bits = sm.adj[t][w];
#pragma unroll
      for (int b = 0; b < 32; ++b) {
        float x = leaky(f1i + sm.f2[(w << 5) + b]);
        x = ((bits >> b) & 1u) ? x : kNegInf;
        m = fmaxf(m, x);
      }
    }
    float l = 0.0f;
#pragma unroll
    for (int w = 0; w < 4; ++w) {
      const unsigned int bits = sm.adj[t][w];
#pragma unroll
      for (int b = 0; b < 32; ++b) {
        float x = leaky(f1i + sm.f2[(w << 5) + b]);
        x = ((bits >> b) & 1u) ? x : kNegInf;
        l += expf(x - m);  // all-masked row: exp(0)=1 each -> uniform softmax (matches jax)
      }
    }
    sm.mrow[t] = m;
    sm.linv[t] = 1.0f / l;
  }
  __syncthreads();

  // ---------------- fill A_T (normalized attention, transposed) ----------------
  {
    const int i  = t & 127;
    const int jb = (t >> 7) << 6;  // 0 or 64
    const float f1i = sm.f1[i] + ab;
    const float m  = sm.mrow[i];
    const float li = sm.linv[i];
#pragma unroll
    for (int w = 0; w < 2; ++w) {
      const unsigned int bits = sm.adj[i][(jb >> 5) + w];
#pragma unroll
      for (int b = 0; b < 32; ++b) {
        const int j = jb + (w << 5) + b;
        float x = leaky(f1i + sm.f2[j]);
        x = ((bits >> b) & 1u) ? x : kNegInf;
        sm.A_T[j][i] = expf(x - m) * li;  // masked -> exp(-1e9 - m) == 0
      }
    }
  }
  __syncthreads();

  // ---------------- matmul2: h' = A @ Wh ----------------
#pragma unroll
  for (int r = 0; r < 8; ++r)
#pragma unroll
    for (int c = 0; c < 8; ++c) acc[r][c] = 0.0f;

#pragma unroll 2
  for (int j = 0; j < 128; ++j) {
    float af[8], bf[8];
    {
      float4 v;
      v = *(const float4*)(&sm.A_T[j][i0]);     af[0]=v.x; af[1]=v.y; af[2]=v.z; af[3]=v.w;
      v = *(const float4*)(&sm.A_T[j][i0 + 4]); af[4]=v.x; af[5]=v.y; af[6]=v.z; af[7]=v.w;
      v = *(const float4*)(&sm.Wh[j][g0]);      bf[0]=v.x; bf[1]=v.y; bf[2]=v.z; bf[3]=v.w;
      v = *(const float4*)(&sm.Wh[j][g0 + 4]);  bf[4]=v.x; bf[5]=v.y; bf[6]=v.z; bf[7]=v.w;
    }
#pragma unroll
    for (int r = 0; r < 8; ++r)
#pragma unroll
      for (int c = 0; c < 8; ++c) acc[r][c] = fmaf(af[r], bf[c], acc[r][c]);
  }

  // ---------------- elu epilogue + store ----------------
  float* oblk = out + (size_t)bs * (128 * 128);
#pragma unroll
  for (int r = 0; r < 8; ++r) {
    float v[8];
#pragma unroll
    for (int c = 0; c < 8; ++c) {
      const float x = acc[r][c];
      v[c] = x > 0.0f ? x : expm1f(x);
    }
    *(float4*)(oblk + (size_t)(i0 + r) * 128 + g0)     = make_float4(v[0], v[1], v[2], v[3]);
    *(float4*)(oblk + (size_t)(i0 + r) * 128 + g0 + 4) = make_float4(v[4], v[5], v[6], v[7]);
  }
}

}  // namespace

extern "C" void kernel_launch(void* const* d_in, const int* in_sizes, int n_in,
                              void* d_out, int out_size, void* d_ws, size_t ws_size,
                              hipStream_t stream) {
  const float* h   = (const float*)d_in[0];
  const float* Ww  = (const float*)d_in[1];
  const float* Wb  = (const float*)d_in[2];
  const float* a1v = (const float*)d_in[3];
  const float* a2v = (const float*)d_in[4];
  const float* ab  = (const float*)d_in[5];
  const int*   adj = (const int*)d_in[6];
  float* out = (float*)d_out;

  const int BS = in_sizes[0] / (128 * 128);  // 1024
  hipLaunchKernelGGL(gat_fused, dim3(BS), dim3(256), 0, stream,
                     h, Ww, Wb, a1v, a2v, ab, adj, out);
}

// Round 3
// 72.912 us; speedup vs baseline: 3.1529x; 3.1529x over previous
//
#include <hip/hip_runtime.h>
#include <cmath>

namespace {

typedef __attribute__((ext_vector_type(8))) short bf16x8;
typedef __attribute__((ext_vector_type(4))) float f32x4;

constexpr float kNegInf = -1000000000.0f;
constexpr float kSlope  = 0.2f;

__device__ __forceinline__ unsigned short f2bf(float x) {
  unsigned int u = __float_as_uint(x);
  u = (u + 0x7FFFu + ((u >> 16) & 1u)) >> 16;  // RNE truncation to bf16
  return (unsigned short)u;
}
__device__ __forceinline__ float bf2f(unsigned short b) {
  return __uint_as_float(((unsigned int)b) << 16);
}

// ---------------- ws layout ----------------
// [0)       ushort wf_hi[16384]  W in B-frag order, hi bf16   (32 KB)
// [32768)   ushort wf_lo[16384]  W in B-frag order, lo bf16   (32 KB)
// [65536)   uint   adjp[512]     bit-packed adjacency          (2 KB)

__global__ void prep(const float* __restrict__ Ww, const int* __restrict__ adj,
                     unsigned short* __restrict__ wf_hi,
                     unsigned short* __restrict__ wf_lo,
                     unsigned int* __restrict__ adjp) {
  const int tid = blockIdx.x * 256 + threadIdx.x;
  if (tid < 16384) {
    // frag order: Wf[g][kc][lane][j] = W[kc*32 + (lane>>4)*8 + j][g*16 + (lane&15)]
    const int j = tid & 7, l = (tid >> 3) & 63, kc = (tid >> 9) & 3, g = tid >> 11;
    const int k = kc * 32 + ((l >> 4) << 3) + j;
    const int col = g * 16 + (l & 15);
    const float x = Ww[k * 128 + col];
    const unsigned short hi = f2bf(x);
    wf_hi[tid] = hi;
    wf_lo[tid] = f2bf(x - bf2f(hi));
  }
  if (tid < 512) {
    const int row = tid >> 2, wd = tid & 3;
    const int* ap = adj + row * 128 + wd * 32;
    unsigned int bits = 0u;
#pragma unroll
    for (int b = 0; b < 32; ++b) bits |= (ap[b] != 0 ? (1u << b) : 0u);
    adjp[tid] = bits;
  }
}

struct alignas(16) SMem {
  unsigned short Whs[8][4][64][8];  // 32 KB: B-frag order, Whs[g][kc][lane][j]
  float f1s[128];
  float f2s[128];
  float pmax[2][128];
  float psum[2][128];
  unsigned int adjs[512];           // [row*4 + wd]
};  // ~37 KB

__global__ __launch_bounds__(256, 2) void gat_mfma(
    const float* __restrict__ h,     // [BS][128][128]
    const float* __restrict__ Wb,    // [128]
    const float* __restrict__ a1v,   // [128]
    const float* __restrict__ a2v,   // [128]
    const float* __restrict__ abp,   // [1]
    const unsigned short* __restrict__ wf_hi,
    const unsigned short* __restrict__ wf_lo,
    const unsigned int* __restrict__ adjp,
    float* __restrict__ out) {       // [BS][128][128]
  __shared__ SMem sm;
  const int t    = threadIdx.x;
  const int lane = t & 63;
  const int w    = t >> 6;       // wave 0..3
  const int lr   = lane & 15;    // row-in-tile (A) / col-in-tile (B,C)
  const int lg   = lane >> 4;    // 0..3
  const int bs   = blockIdx.x;
  const float ab = abp[0];

  // stage packed adjacency (2 words / thread)
  *(uint2*)(sm.adjs + t * 2) = *(const uint2*)(adjp + t * 2);

  // ---------------- matmul1: Wh = h @ W  (hi/lo split, 3 MFMAs) ----------------
  const float* hblk = h + (size_t)bs * 16384;
  const int R0 = w * 32;  // this wave's 32 output rows

  bf16x8 ha[2][4], la[2][4];  // A-frags of h: [row-tile][k-chunk]
#pragma unroll
  for (int rt = 0; rt < 2; ++rt)
#pragma unroll
    for (int kc = 0; kc < 4; ++kc) {
      const float* p = hblk + (R0 + rt * 16 + lr) * 128 + kc * 32 + lg * 8;
      f32x4 v0 = *(const f32x4*)p;
      f32x4 v1 = *(const f32x4*)(p + 4);
      bf16x8 hi, lo;
#pragma unroll
      for (int q = 0; q < 4; ++q) {
        unsigned short hb = f2bf(v0[q]);
        hi[q] = (short)hb;
        lo[q] = (short)f2bf(v0[q] - bf2f(hb));
        unsigned short hb2 = f2bf(v1[q]);
        hi[q + 4] = (short)hb2;
        lo[q + 4] = (short)f2bf(v1[q] - bf2f(hb2));
      }
      ha[rt][kc] = hi;
      la[rt][kc] = lo;
    }

  f32x4 acc[2][8];
#pragma unroll
  for (int rt = 0; rt < 2; ++rt)
#pragma unroll
    for (int g = 0; g < 8; ++g) acc[rt][g] = (f32x4){0.f, 0.f, 0.f, 0.f};

#pragma unroll
  for (int g = 0; g < 8; ++g) {
    bf16x8 bh[4], bl[4];
#pragma unroll
    for (int kc = 0; kc < 4; ++kc) {
      bh[kc] = *(const bf16x8*)(wf_hi + ((g * 4 + kc) * 64 + lane) * 8);
      bl[kc] = *(const bf16x8*)(wf_lo + ((g * 4 + kc) * 64 + lane) * 8);
    }
#pragma unroll
    for (int kc = 0; kc < 4; ++kc)
#pragma unroll
      for (int rt = 0; rt < 2; ++rt) {
        acc[rt][g] = __builtin_amdgcn_mfma_f32_16x16x32_bf16(ha[rt][kc], bh[kc], acc[rt][g], 0, 0, 0);
        acc[rt][g] = __builtin_amdgcn_mfma_f32_16x16x32_bf16(la[rt][kc], bh[kc], acc[rt][g], 0, 0, 0);
        acc[rt][g] = __builtin_amdgcn_mfma_f32_16x16x32_bf16(ha[rt][kc], bl[kc], acc[rt][g], 0, 0, 0);
      }
  }

  // ---- bias + f1/f2 (16-lane shuffle reduce) + Wh -> LDS (B-frag order, bf16) ----
  float wbc[8], a1c[8], a2c[8];
#pragma unroll
  for (int g = 0; g < 8; ++g) {
    wbc[g] = Wb[g * 16 + lr];
    a1c[g] = a1v[g * 16 + lr];
    a2c[g] = a2v[g * 16 + lr];
  }
#pragma unroll
  for (int rt = 0; rt < 2; ++rt) {
#pragma unroll
    for (int r = 0; r < 4; ++r) {
      // C/D layout: row = R0 + rt*16 + lg*4 + r, col = g*16 + lr
      float s1 = 0.f, s2 = 0.f;
#pragma unroll
      for (int g = 0; g < 8; ++g) {
        float a = acc[rt][g][r] + wbc[g];
        acc[rt][g][r] = a;
        s1 = fmaf(a, a1c[g], s1);
        s2 = fmaf(a, a2c[g], s2);
      }
#pragma unroll
      for (int m = 8; m >= 1; m >>= 1) {
        s1 += __shfl_xor(s1, m);
        s2 += __shfl_xor(s2, m);
      }
      if (lr == 0) {
        const int row = R0 + rt * 16 + lg * 4 + r;
        sm.f1s[row] = s1;
        sm.f2s[row] = s2;
      }
    }
    // pack this row-tile's Wh into B-frag order
#pragma unroll
    for (int g = 0; g < 8; ++g) {
      ushort4 pk;
      pk.x = f2bf(acc[rt][g][0]);
      pk.y = f2bf(acc[rt][g][1]);
      pk.z = f2bf(acc[rt][g][2]);
      pk.w = f2bf(acc[rt][g][3]);
      const int lp = (2 * rt + (lg >> 1)) * 16 + lr;
      const int jb = (lg & 1) * 4;
      *(ushort4*)(&sm.Whs[g][w][lp][jb]) = pk;
    }
  }
  __syncthreads();

  // ---------------- softmax stats: 2 threads per row ----------------
  const int srow = t & 127;
  const int hf   = t >> 7;  // column half
  {
    const float f1i = sm.f1s[srow] + ab;
    const unsigned int aw0 = sm.adjs[srow * 4 + hf * 2];
    const unsigned int aw1 = sm.adjs[srow * 4 + hf * 2 + 1];
    float m = kNegInf;
#pragma unroll
    for (int jb = 0; jb < 16; ++jb) {
      f32x4 fv = *(const f32x4*)(&sm.f2s[hf * 64 + jb * 4]);
      const unsigned int aw = (jb < 8) ? aw0 : aw1;
#pragma unroll
      for (int q = 0; q < 4; ++q) {
        float x = f1i + fv[q];
        x = x >= 0.f ? x : kSlope * x;
        x = ((aw >> ((jb * 4 + q) & 31)) & 1u) ? x : kNegInf;
        m = fmaxf(m, x);
      }
    }
    sm.pmax[hf][srow] = m;
  }
  __syncthreads();
  {
    const float f1i = sm.f1s[srow] + ab;
    const float m = fmaxf(sm.pmax[0][srow], sm.pmax[1][srow]);
    const unsigned int aw0 = sm.adjs[srow * 4 + hf * 2];
    const unsigned int aw1 = sm.adjs[srow * 4 + hf * 2 + 1];
    float s = 0.f;
#pragma unroll
    for (int jb = 0; jb < 16; ++jb) {
      f32x4 fv = *(const f32x4*)(&sm.f2s[hf * 64 + jb * 4]);
      const unsigned int aw = (jb < 8) ? aw0 : aw1;
#pragma unroll
      for (int q = 0; q < 4; ++q) {
        float x = f1i + fv[q];
        x = x >= 0.f ? x : kSlope * x;
        x = ((aw >> ((jb * 4 + q) & 31)) & 1u) ? x : kNegInf;
        s += __expf(x - m);  // all-masked row -> exp(0) each -> uniform (matches jax)
      }
    }
    sm.psum[hf][srow] = s;
  }
  __syncthreads();

  // ---------------- A-frags (attention, bf16) + matmul2: h' = A @ Wh ----------------
  bf16x8 af[2][4];
#pragma unroll
  for (int rt = 0; rt < 2; ++rt) {
    const int row = R0 + rt * 16 + lr;  // A-frag row = lane&15
    const float f1i = sm.f1s[row] + ab;
    const float m  = fmaxf(sm.pmax[0][row], sm.pmax[1][row]);
    const float li = 1.0f / (sm.psum[0][row] + sm.psum[1][row]);
#pragma unroll
    for (int kc = 0; kc < 4; ++kc) {
      const unsigned int aw = sm.adjs[row * 4 + kc];
      f32x4 fv0 = *(const f32x4*)(&sm.f2s[kc * 32 + lg * 8]);
      f32x4 fv1 = *(const f32x4*)(&sm.f2s[kc * 32 + lg * 8 + 4]);
      bf16x8 pa;
#pragma unroll
      for (int q = 0; q < 8; ++q) {
        const float fj = (q < 4) ? fv0[q] : fv1[q - 4];
        float x = f1i + fj;
        x = x >= 0.f ? x : kSlope * x;
        x = ((aw >> (lg * 8 + q)) & 1u) ? x : kNegInf;
        pa[q] = (short)f2bf(__expf(x - m) * li);
      }
      af[rt][kc] = pa;
    }
  }

  f32x4 acc2[2][8];
#pragma unroll
  for (int rt = 0; rt < 2; ++rt)
#pragma unroll
    for (int g = 0; g < 8; ++g) acc2[rt][g] = (f32x4){0.f, 0.f, 0.f, 0.f};

#pragma unroll
  for (int g = 0; g < 8; ++g)
#pragma unroll
    for (int kc = 0; kc < 4; ++kc) {
      bf16x8 bw = *(const bf16x8*)(&sm.Whs[g][kc][lane][0]);
#pragma unroll
      for (int rt = 0; rt < 2; ++rt)
        acc2[rt][g] = __builtin_amdgcn_mfma_f32_16x16x32_bf16(af[rt][kc], bw, acc2[rt][g], 0, 0, 0);
    }

  // ---------------- elu epilogue + store ----------------
  float* oblk = out + (size_t)bs * 16384;
#pragma unroll
  for (int rt = 0; rt < 2; ++rt)
#pragma unroll
    for (int r = 0; r < 4; ++r) {
      const int row = R0 + rt * 16 + lg * 4 + r;
#pragma unroll
      for (int g = 0; g < 8; ++g) {
        const float x = acc2[rt][g][r];
        oblk[row * 128 + g * 16 + lr] = x > 0.f ? x : expm1f(x);
      }
    }
}

}  // namespace

extern "C" void kernel_launch(void* const* d_in, const int* in_sizes, int n_in,
                              void* d_out, int out_size, void* d_ws, size_t ws_size,
                              hipStream_t stream) {
  const float* h   = (const float*)d_in[0];
  const float* Ww  = (const float*)d_in[1];
  const float* Wb  = (const float*)d_in[2];
  const float* a1v = (const float*)d_in[3];
  const float* a2v = (const float*)d_in[4];
  const float* ab  = (const float*)d_in[5];
  const int*   adj = (const int*)d_in[6];
  float* out = (float*)d_out;

  unsigned short* wf_hi = (unsigned short*)d_ws;
  unsigned short* wf_lo = wf_hi + 16384;
  unsigned int*   adjp  = (unsigned int*)((char*)d_ws + 65536);

  hipLaunchKernelGGL(prep, dim3(64), dim3(256), 0, stream, Ww, adj, wf_hi, wf_lo, adjp);

  const int BS = in_sizes[0] / 16384;  // 1024
  hipLaunchKernelGGL(gat_mfma, dim3(BS), dim3(256), 0, stream,
                     h, Wb, a1v, a2v, ab, wf_hi, wf_lo, adjp, out);
}

// Round 4
// 61.781 us; speedup vs baseline: 3.7209x; 1.1802x over previous
//
#include <hip/hip_runtime.h>
#include <cmath>

namespace {

typedef __attribute__((ext_vector_type(8))) short bf16x8;
typedef __attribute__((ext_vector_type(4))) float f32x4;

constexpr float kNegInf = -1000000000.0f;
constexpr float kSlope  = 0.2f;

__device__ __forceinline__ unsigned short f2bf(float x) {
  unsigned int u = __float_as_uint(x);
  u = (u + 0x7FFFu + ((u >> 16) & 1u)) >> 16;  // RNE truncation to bf16
  return (unsigned short)u;
}
__device__ __forceinline__ float bf2f(unsigned short b) {
  return __uint_as_float(((unsigned int)b) << 16);
}

// ---------------- ws layout ----------------
// [0)      ushort wf_hi[18432]  W|wa in B-frag order (9 tiles), hi bf16 (36864 B)
// [36864)  ushort wf_lo[18432]  lo bf16                                 (36864 B)
// [73728)  uint   adjp[512]     bit-packed adjacency                    (2048 B)
// [75776)  float  wa1[128]
// [76288)  float  wa2[128]
// [76800)  float  ba[2]         {Wb.a1, Wb.a2}

__global__ void prep1(const float* __restrict__ Ww, const float* __restrict__ Wb,
                      const float* __restrict__ a1v, const float* __restrict__ a2v,
                      float* __restrict__ wa1, float* __restrict__ wa2,
                      float* __restrict__ ba) {
  const int k = threadIdx.x;
  if (k < 128) {
    float s1 = 0.f, s2 = 0.f;
    for (int g = 0; g < 128; ++g) {
      const float w = Ww[k * 128 + g];
      s1 = fmaf(w, a1v[g], s1);
      s2 = fmaf(w, a2v[g], s2);
    }
    wa1[k] = s1;
    wa2[k] = s2;
  }
  if (k == 128) {
    float s1 = 0.f, s2 = 0.f;
    for (int g = 0; g < 128; ++g) {
      s1 = fmaf(Wb[g], a1v[g], s1);
      s2 = fmaf(Wb[g], a2v[g], s2);
    }
    ba[0] = s1;
    ba[1] = s2;
  }
}

__global__ void prep2(const float* __restrict__ Ww, const int* __restrict__ adj,
                      const float* __restrict__ wa1, const float* __restrict__ wa2,
                      unsigned short* __restrict__ wf_hi,
                      unsigned short* __restrict__ wf_lo,
                      unsigned int* __restrict__ adjp) {
  const int tid = blockIdx.x * 256 + threadIdx.x;
  if (tid < 18432) {
    // frag order: Wf[g][kc][lane][j] = B[k = kc*32 + (lane>>4)*8 + j][col = g*16 + (lane&15)]
    const int j = tid & 7, l = (tid >> 3) & 63, kc = (tid >> 9) & 3, g = tid >> 11;
    const int k = kc * 32 + ((l >> 4) << 3) + j;
    const int c = l & 15;
    float x;
    if (g < 8) x = Ww[k * 128 + g * 16 + c];
    else       x = (c == 0) ? wa1[k] : (c == 1) ? wa2[k] : 0.f;
    const unsigned short hi = f2bf(x);
    wf_hi[tid] = hi;
    wf_lo[tid] = f2bf(x - bf2f(hi));
  }
  if (tid < 512) {
    const int row = tid >> 2, wd = tid & 3;
    const int* ap = adj + row * 128 + wd * 32;
    unsigned int bits = 0u;
#pragma unroll
    for (int b = 0; b < 32; ++b) bits |= (ap[b] != 0 ? (1u << b) : 0u);
    adjp[tid] = bits;
  }
}

struct alignas(16) SMem {
  unsigned short Whs[9][4][64][8];  // 36864 B: B-frag order; tile 8 = ones col
  float f1s[128];                   // 512
  float f2s[128];                   // 512
  float pmax[2][128];               // 1024
  unsigned int adjs[512];           // 2048   -> total 40960 B (4 blocks = 160 KiB)
};

__global__ __launch_bounds__(256, 4) void gat_mfma(
    const float* __restrict__ h,     // [BS][128][128]
    const float* __restrict__ Wb,    // [128]
    const float* __restrict__ abp,   // [1]
    const unsigned short* __restrict__ wf_hi,
    const unsigned short* __restrict__ wf_lo,
    const unsigned int* __restrict__ adjp,
    const float* __restrict__ ba,
    float* __restrict__ out) {       // [BS][128][128]
  __shared__ SMem sm;
  const int t    = threadIdx.x;
  const int lane = t & 63;
  const int w    = t >> 6;       // wave 0..3
  const int lr   = lane & 15;    // row-in-tile (A) / col-in-tile (B,C)
  const int lg   = lane >> 4;    // 0..3
  const int bs   = blockIdx.x;
  const float ab = abp[0];

  // stage packed adjacency (2 words / thread)
  *(uint2*)(sm.adjs + t * 2) = *(const uint2*)(adjp + t * 2);

  // ones tile for matmul2 row-sums: B[k][col] = (col==0) ? 1 : 0
  {
    const int kc_i = t >> 6, ln = t & 63;
    const unsigned short v = ((ln & 15) == 0) ? (unsigned short)0x3F80 : (unsigned short)0;
    ushort4 pk = make_ushort4(v, v, v, v);
    *(ushort4*)(&sm.Whs[8][kc_i][ln][0]) = pk;
    *(ushort4*)(&sm.Whs[8][kc_i][ln][4]) = pk;
  }

  // ---------------- matmul1: [Wh | f1 f2] = h @ [W | wa1 wa2]  (hi/lo, 3 MFMAs) ----------------
  const float* hblk = h + (size_t)bs * 16384;
  const int R0 = w * 32;  // this wave's 32 output rows

  bf16x8 ha[2][4], la[2][4];  // A-frags of h: [row-tile][k-chunk]
#pragma unroll
  for (int rt = 0; rt < 2; ++rt)
#pragma unroll
    for (int kc = 0; kc < 4; ++kc) {
      const float* p = hblk + (R0 + rt * 16 + lr) * 128 + kc * 32 + lg * 8;
      f32x4 v0 = *(const f32x4*)p;
      f32x4 v1 = *(const f32x4*)(p + 4);
      bf16x8 hi, lo;
#pragma unroll
      for (int q = 0; q < 4; ++q) {
        unsigned short hb = f2bf(v0[q]);
        hi[q] = (short)hb;
        lo[q] = (short)f2bf(v0[q] - bf2f(hb));
        unsigned short hb2 = f2bf(v1[q]);
        hi[q + 4] = (short)hb2;
        lo[q + 4] = (short)f2bf(v1[q] - bf2f(hb2));
      }
      ha[rt][kc] = hi;
      la[rt][kc] = lo;
    }

  f32x4 acc[2][9];
#pragma unroll
  for (int rt = 0; rt < 2; ++rt)
#pragma unroll
    for (int g = 0; g < 9; ++g) acc[rt][g] = (f32x4){0.f, 0.f, 0.f, 0.f};

#pragma unroll
  for (int g = 0; g < 9; ++g) {
#pragma unroll
    for (int kc = 0; kc < 4; ++kc) {
      const bf16x8 bh = *(const bf16x8*)(wf_hi + ((g * 4 + kc) * 64 + lane) * 8);
      const bf16x8 bl = *(const bf16x8*)(wf_lo + ((g * 4 + kc) * 64 + lane) * 8);
#pragma unroll
      for (int rt = 0; rt < 2; ++rt) {
        acc[rt][g] = __builtin_amdgcn_mfma_f32_16x16x32_bf16(ha[rt][kc], bh, acc[rt][g], 0, 0, 0);
        acc[rt][g] = __builtin_amdgcn_mfma_f32_16x16x32_bf16(la[rt][kc], bh, acc[rt][g], 0, 0, 0);
        acc[rt][g] = __builtin_amdgcn_mfma_f32_16x16x32_bf16(ha[rt][kc], bl, acc[rt][g], 0, 0, 0);
      }
    }
  }

  // ---- bias + f1/f2 scatter + Wh -> LDS (B-frag order, bf16) ----
  float wbc[8];
#pragma unroll
  for (int g = 0; g < 8; ++g) wbc[g] = Wb[g * 16 + lr];
  const float ba1 = ba[0], ba2 = ba[1];

#pragma unroll
  for (int rt = 0; rt < 2; ++rt) {
#pragma unroll
    for (int r = 0; r < 4; ++r) {
      // C/D layout: row = R0 + rt*16 + lg*4 + r, col = g*16 + lr
#pragma unroll
      for (int g = 0; g < 8; ++g) acc[rt][g][r] += wbc[g];
      const int row = R0 + rt * 16 + lg * 4 + r;
      if (lr == 0)      sm.f1s[row] = acc[rt][8][r] + ba1;
      else if (lr == 1) sm.f2s[row] = acc[rt][8][r] + ba2;
    }
    // pack this row-tile's Wh into B-frag order (wave w owns kc=w slice)
#pragma unroll
    for (int g = 0; g < 8; ++g) {
      ushort4 pk;
      pk.x = f2bf(acc[rt][g][0]);
      pk.y = f2bf(acc[rt][g][1]);
      pk.z = f2bf(acc[rt][g][2]);
      pk.w = f2bf(acc[rt][g][3]);
      const int lp = (2 * rt + (lg >> 1)) * 16 + lr;
      const int jb = (lg & 1) * 4;
      *(ushort4*)(&sm.Whs[g][w][lp][jb]) = pk;
    }
  }
  __syncthreads();

  // ---------------- softmax max: 2 threads per row ----------------
  const int srow = t & 127;
  const int hf   = t >> 7;  // column half
  {
    const float f1i = sm.f1s[srow] + ab;
    const unsigned int aw0 = sm.adjs[srow * 4 + hf * 2];
    const unsigned int aw1 = sm.adjs[srow * 4 + hf * 2 + 1];
    float m = kNegInf;
#pragma unroll
    for (int jb = 0; jb < 16; ++jb) {
      f32x4 fv = *(const f32x4*)(&sm.f2s[hf * 64 + jb * 4]);
      const unsigned int aw = (jb < 8) ? aw0 : aw1;
#pragma unroll
      for (int q = 0; q < 4; ++q) {
        float x = f1i + fv[q];
        x = x >= 0.f ? x : kSlope * x;
        x = ((aw >> ((jb * 4 + q) & 31)) & 1u) ? x : kNegInf;
        m = fmaxf(m, x);
      }
    }
    sm.pmax[hf][srow] = m;
  }
  __syncthreads();

  // ---------------- A-frags (unnormalized P, bf16) ----------------
  bf16x8 af[2][4];
#pragma unroll
  for (int rt = 0; rt < 2; ++rt) {
    const int row = R0 + rt * 16 + lr;  // A-frag row = lane&15
    const float f1i = sm.f1s[row] + ab;
    const float m   = fmaxf(sm.pmax[0][row], sm.pmax[1][row]);
#pragma unroll
    for (int kc = 0; kc < 4; ++kc) {
      const unsigned int aw = sm.adjs[row * 4 + kc];
      f32x4 fv0 = *(const f32x4*)(&sm.f2s[kc * 32 + lg * 8]);
      f32x4 fv1 = *(const f32x4*)(&sm.f2s[kc * 32 + lg * 8 + 4]);
      bf16x8 pa;
#pragma unroll
      for (int q = 0; q < 8; ++q) {
        const float fj = (q < 4) ? fv0[q] : fv1[q - 4];
        float x = f1i + fj;
        x = x >= 0.f ? x : kSlope * x;
        x = ((aw >> (lg * 8 + q)) & 1u) ? x : kNegInf;
        pa[q] = (short)f2bf(__expf(x - m));  // all-masked row -> exp(0)=1 (uniform, matches jax)
      }
      af[rt][kc] = pa;
    }
  }

  // ---------------- matmul2: [h'·l | l] = P @ [Wh | 1] ----------------
  f32x4 acc2[2][9];
#pragma unroll
  for (int rt = 0; rt < 2; ++rt)
#pragma unroll
    for (int g = 0; g < 9; ++g) acc2[rt][g] = (f32x4){0.f, 0.f, 0.f, 0.f};

#pragma unroll
  for (int g = 0; g < 9; ++g)
#pragma unroll
    for (int kc = 0; kc < 4; ++kc) {
      bf16x8 bw = *(const bf16x8*)(&sm.Whs[g][kc][lane][0]);
#pragma unroll
      for (int rt = 0; rt < 2; ++rt)
        acc2[rt][g] = __builtin_amdgcn_mfma_f32_16x16x32_bf16(af[rt][kc], bw, acc2[rt][g], 0, 0, 0);
    }

  // ---------------- normalize + elu epilogue + store ----------------
  float* oblk = out + (size_t)bs * 16384;
#pragma unroll
  for (int rt = 0; rt < 2; ++rt)
#pragma unroll
    for (int r = 0; r < 4; ++r) {
      const int row = R0 + rt * 16 + lg * 4 + r;
      const float lsum = __shfl(acc2[rt][8][r], lane & 48);  // lr==0 lane of this lg
      const float inv  = __builtin_amdgcn_rcpf(lsum);
#pragma unroll
      for (int g = 0; g < 8; ++g) {
        const float x = acc2[rt][g][r] * inv;
        oblk[row * 128 + g * 16 + lr] = x > 0.f ? x : __expf(x) - 1.0f;
      }
    }
}

}  // namespace

extern "C" void kernel_launch(void* const* d_in, const int* in_sizes, int n_in,
                              void* d_out, int out_size, void* d_ws, size_t ws_size,
                              hipStream_t stream) {
  const float* h   = (const float*)d_in[0];
  const float* Ww  = (const float*)d_in[1];
  const float* Wb  = (const float*)d_in[2];
  const float* a1v = (const float*)d_in[3];
  const float* a2v = (const float*)d_in[4];
  const float* ab  = (const float*)d_in[5];
  const int*   adj = (const int*)d_in[6];
  float* out = (float*)d_out;

  unsigned short* wf_hi = (unsigned short*)d_ws;
  unsigned short* wf_lo = wf_hi + 18432;
  unsigned int*   adjp  = (unsigned int*)((char*)d_ws + 73728);
  float*          wa1   = (float*)((char*)d_ws + 75776);
  float*          wa2   = (float*)((char*)d_ws + 76288);
  float*          ba    = (float*)((char*)d_ws + 76800);

  hipLaunchKernelGGL(prep1, dim3(1), dim3(256), 0, stream, Ww, Wb, a1v, a2v, wa1, wa2, ba);
  hipLaunchKernelGGL(prep2, dim3(72), dim3(256), 0, stream, Ww, adj, wa1, wa2, wf_hi, wf_lo, adjp);

  const int BS = in_sizes[0] / 16384;  // 1024
  hipLaunchKernelGGL(gat_mfma, dim3(BS), dim3(256), 0, stream,
                     h, Wb, ab, wf_hi, wf_lo, adjp, ba, out);
}

// Round 5
// 46.484 us; speedup vs baseline: 4.9454x; 1.3291x over previous
//
#include <hip/hip_runtime.h>
#include <hip/hip_bf16.h>
#include <cmath>

namespace {

typedef __attribute__((ext_vector_type(8))) short bf16x8;
typedef __attribute__((ext_vector_type(4))) float f32x4;

constexpr float kNegInf = -1000000000.0f;
constexpr float kSlope  = 0.2f;

__device__ __forceinline__ unsigned short f2bf(float x) {
  unsigned int u = __float_as_uint(x);
  u = (u + 0x7FFFu + ((u >> 16) & 1u)) >> 16;  // RNE
  return (unsigned short)u;
}
__device__ __forceinline__ float bf2f(unsigned short b) {
  return __uint_as_float(((unsigned int)b) << 16);
}
// packed pair: returns (bf16(b)<<16) | bf16(a)  via v_cvt_pk_bf16_f32
__device__ __forceinline__ unsigned int f2bf2(float a, float b) {
  __hip_bfloat162 t = __float22bfloat162_rn(float2{a, b});
  union { __hip_bfloat162 h; unsigned int u; } c;
  c.h = t;
  return c.u;
}

// ---------------- ws layout ----------------
// [0)      ushort wf[18432]   [W | wa1 wa2] in B-frag order, bf16  (36864 B)
// [36864)  uint   adjp[512]   bit-packed adjacency                 (2048 B)
// [38912)  float  wa1[128]
// [39424)  float  wa2[128]
// [39936)  float  ba[2]       {Wb.a1, Wb.a2}

__global__ void prep1(const float* __restrict__ Ww, const float* __restrict__ Wb,
                      const float* __restrict__ a1v, const float* __restrict__ a2v,
                      float* __restrict__ wa1, float* __restrict__ wa2,
                      float* __restrict__ ba) {
  const int k = threadIdx.x;
  if (k < 128) {
    float s1 = 0.f, s2 = 0.f;
    for (int g = 0; g < 128; ++g) {
      const float w = Ww[k * 128 + g];
      s1 = fmaf(w, a1v[g], s1);
      s2 = fmaf(w, a2v[g], s2);
    }
    wa1[k] = s1;
    wa2[k] = s2;
  }
  if (k == 128) {
    float s1 = 0.f, s2 = 0.f;
    for (int g = 0; g < 128; ++g) {
      s1 = fmaf(Wb[g], a1v[g], s1);
      s2 = fmaf(Wb[g], a2v[g], s2);
    }
    ba[0] = s1;
    ba[1] = s2;
  }
}

__global__ void prep2(const float* __restrict__ Ww, const int* __restrict__ adj,
                      const float* __restrict__ wa1, const float* __restrict__ wa2,
                      unsigned short* __restrict__ wf, unsigned int* __restrict__ adjp) {
  const int tid = blockIdx.x * 256 + threadIdx.x;
  if (tid < 18432) {
    // frag order: wf[g][kc][lane][j] = B[k = kc*32 + (lane>>4)*8 + j][col = g*16 + (lane&15)]
    const int j = tid & 7, l = (tid >> 3) & 63, kc = (tid >> 9) & 3, g = tid >> 11;
    const int k = kc * 32 + ((l >> 4) << 3) + j;
    const int c = l & 15;
    float x;
    if (g < 8) x = Ww[k * 128 + g * 16 + c];
    else       x = (c == 0) ? wa1[k] : (c == 1) ? wa2[k] : 0.f;
    wf[tid] = f2bf(x);
  }
  if (tid < 512) {
    const int row = tid >> 2, wd = tid & 3;
    const int* ap = adj + row * 128 + wd * 32;
    unsigned int bits = 0u;
#pragma unroll
    for (int b = 0; b < 32; ++b) bits |= (ap[b] != 0 ? (1u << b) : 0u);
    adjp[tid] = bits;
  }
}

struct SMemA {
  unsigned short Whs[8][4][64][8];  // 32768 B: Wh in B-frag order
  float f1s[128];                   // 512
  float f2s[128];                   // 512
  unsigned int adjs[512];           // 2048
};
union SMemU {
  SMemA a;
  float stage[4][16][132];          // 33792 B — aliases Whs+f1s+f2s (all dead by then)
};                                   // sizeof = 35840 -> 4 blocks/CU

__global__ __launch_bounds__(256, 4) void gat_mfma(
    const float* __restrict__ h,     // [BS][128][128]
    const float* __restrict__ Wb,    // [128]
    const float* __restrict__ abp,   // [1]
    const unsigned short* __restrict__ wf,
    const unsigned int* __restrict__ adjp,
    const float* __restrict__ ba,
    float* __restrict__ out) {       // [BS][128][128]
  __shared__ SMemU smu;
  SMemA& sm = smu.a;
  const int t    = threadIdx.x;
  const int lane = t & 63;
  const int w    = t >> 6;       // wave 0..3
  const int lr   = lane & 15;
  const int lg   = lane >> 4;    // 0..3
  const int bs   = blockIdx.x;
  const float ab = abp[0];

  // stage packed adjacency (2 words / thread)
  *(uint2*)(sm.adjs + t * 2) = *(const uint2*)(adjp + t * 2);

  // ---------------- matmul1: [Wh | f1 f2] = bf16(h) @ bf16([W | wa1 wa2]) ----------------
  const float* hblk = h + (size_t)bs * 16384;
  const int R0 = w * 32;

  bf16x8 ha[2][4];
#pragma unroll
  for (int rt = 0; rt < 2; ++rt)
#pragma unroll
    for (int kc = 0; kc < 4; ++kc) {
      const float* p = hblk + (R0 + rt * 16 + lr) * 128 + kc * 32 + lg * 8;
      f32x4 v0 = *(const f32x4*)p;
      f32x4 v1 = *(const f32x4*)(p + 4);
      union { bf16x8 v; unsigned int u[4]; } pk;
      pk.u[0] = f2bf2(v0[0], v0[1]);
      pk.u[1] = f2bf2(v0[2], v0[3]);
      pk.u[2] = f2bf2(v1[0], v1[1]);
      pk.u[3] = f2bf2(v1[2], v1[3]);
      ha[rt][kc] = pk.v;
    }

  f32x4 acc[2][9];
#pragma unroll
  for (int rt = 0; rt < 2; ++rt)
#pragma unroll
    for (int g = 0; g < 9; ++g) acc[rt][g] = (f32x4){0.f, 0.f, 0.f, 0.f};

#pragma unroll
  for (int g = 0; g < 9; ++g)
#pragma unroll
    for (int kc = 0; kc < 4; ++kc) {
      const bf16x8 bh = *(const bf16x8*)(wf + ((g * 4 + kc) * 64 + lane) * 8);
      acc[0][g] = __builtin_amdgcn_mfma_f32_16x16x32_bf16(ha[0][kc], bh, acc[0][g], 0, 0, 0);
      acc[1][g] = __builtin_amdgcn_mfma_f32_16x16x32_bf16(ha[1][kc], bh, acc[1][g], 0, 0, 0);
    }

  // ---- bias + f1/f2 scatter + Wh -> LDS (B-frag order, bf16) ----
  float wbc[8];
#pragma unroll
  for (int g = 0; g < 8; ++g) wbc[g] = Wb[g * 16 + lr];
  const float ba1 = ba[0], ba2 = ba[1];

#pragma unroll
  for (int rt = 0; rt < 2; ++rt) {
#pragma unroll
    for (int r = 0; r < 4; ++r) {
      // C/D layout: row = R0 + rt*16 + lg*4 + r, col = g*16 + lr
#pragma unroll
      for (int g = 0; g < 8; ++g) acc[rt][g][r] += wbc[g];
      const int row = R0 + rt * 16 + lg * 4 + r;
      if (lr == 0)      sm.f1s[row] = acc[rt][8][r] + ba1;
      else if (lr == 1) sm.f2s[row] = acc[rt][8][r] + ba2;
    }
#pragma unroll
    for (int g = 0; g < 8; ++g) {
      const unsigned int plo = f2bf2(acc[rt][g][0], acc[rt][g][1]);
      const unsigned int phi = f2bf2(acc[rt][g][2], acc[rt][g][3]);
      const int lp = (2 * rt + (lg >> 1)) * 16 + lr;
      const int jb = (lg & 1) * 4;
      *(uint2*)(&sm.Whs[g][w][lp][jb]) = make_uint2(plo, phi);
    }
  }
  __syncthreads();

  // ---------------- P-build: in-register row max + sum (no LDS pass) ----------------
  bf16x8 af[2][4];
  float rs[2];
#pragma unroll
  for (int rt = 0; rt < 2; ++rt) {
    const int row  = R0 + rt * 16 + lr;   // A-frag row = lane&15
    const float f1i = sm.f1s[row] + ab;
    float xs[4][8];
    float m = kNegInf;
#pragma unroll
    for (int kc = 0; kc < 4; ++kc) {
      const unsigned int aw = sm.adjs[row * 4 + kc];
      f32x4 fv0 = *(const f32x4*)(&sm.f2s[kc * 32 + lg * 8]);
      f32x4 fv1 = *(const f32x4*)(&sm.f2s[kc * 32 + lg * 8 + 4]);
#pragma unroll
      for (int q = 0; q < 8; ++q) {
        float xx = f1i + (q < 4 ? fv0[q] : fv1[q - 4]);
        xx = xx >= 0.f ? xx : kSlope * xx;
        xx = ((aw >> (lg * 8 + q)) & 1u) ? xx : kNegInf;
        xs[kc][q] = xx;
        m = fmaxf(m, xx);
      }
    }
    m = fmaxf(m, __shfl_xor(m, 16));
    m = fmaxf(m, __shfl_xor(m, 32));   // full row max (all-masked row -> m=-1e9 -> P=1 uniform)
    float s = 0.f;
#pragma unroll
    for (int kc = 0; kc < 4; ++kc) {
      union { bf16x8 v; unsigned int u[4]; } pk;
#pragma unroll
      for (int qq = 0; qq < 4; ++qq) {
        const float e0 = __expf(xs[kc][qq * 2]     - m);
        const float e1 = __expf(xs[kc][qq * 2 + 1] - m);
        const unsigned int uu = f2bf2(e0, e1);
        pk.u[qq] = uu;
        s += __uint_as_float(uu << 16) + __uint_as_float(uu & 0xffff0000u);
      }
      af[rt][kc] = pk.v;
    }
    s += __shfl_xor(s, 16);
    s += __shfl_xor(s, 32);            // row sum of bf16-rounded P
    rs[rt] = s;
  }

  // ---------------- matmul2: h'·l = P @ Wh ----------------
  f32x4 acc2[2][8];
#pragma unroll
  for (int rt = 0; rt < 2; ++rt)
#pragma unroll
    for (int g = 0; g < 8; ++g) acc2[rt][g] = (f32x4){0.f, 0.f, 0.f, 0.f};

#pragma unroll
  for (int g = 0; g < 8; ++g)
#pragma unroll
    for (int kc = 0; kc < 4; ++kc) {
      const bf16x8 bw = *(const bf16x8*)(&sm.Whs[g][kc][lane][0]);
      acc2[0][g] = __builtin_amdgcn_mfma_f32_16x16x32_bf16(af[0][kc], bw, acc2[0][g], 0, 0, 0);
      acc2[1][g] = __builtin_amdgcn_mfma_f32_16x16x32_bf16(af[1][kc], bw, acc2[1][g], 0, 0, 0);
    }
  __syncthreads();  // all Whs reads done before stage overwrites it

  // ---------------- normalize + elu + LDS-staged coalesced store ----------------
  float* oblk = out + (size_t)bs * 16384;
#pragma unroll
  for (int rt = 0; rt < 2; ++rt) {
    float inv[4];
#pragma unroll
    for (int r = 0; r < 4; ++r) {
      const float lsum = __shfl(rs[rt], (lane & 48) | (lg * 4 + r));
      inv[r] = __builtin_amdgcn_rcpf(lsum);
    }
#pragma unroll
    for (int r = 0; r < 4; ++r)
#pragma unroll
      for (int g = 0; g < 8; ++g) {
        float v = acc2[rt][g][r] * inv[r];
        v = v > 0.f ? v : __expf(v) - 1.0f;
        smu.stage[w][lg * 4 + r][g * 16 + lr] = v;  // bank-even scalar writes
      }
    // wave-local: DS ops are in-order; compiler inserts lgkmcnt for RAW
#pragma unroll
    for (int sstep = 0; sstep < 8; ++sstep) {
      const int row16 = ((sstep & 1) << 3) + (lane >> 3);
      const int cd    = ((sstep >> 1) << 5) + ((lane & 7) << 2);
      f32x4 vv = *(const f32x4*)(&smu.stage[w][row16][cd]);
      *(f32x4*)(oblk + (size_t)(R0 + rt * 16 + row16) * 128 + cd) = vv;  // 8 rows x 128 B/instr
    }
  }
}

}  // namespace

extern "C" void kernel_launch(void* const* d_in, const int* in_sizes, int n_in,
                              void* d_out, int out_size, void* d_ws, size_t ws_size,
                              hipStream_t stream) {
  const float* h   = (const float*)d_in[0];
  const float* Ww  = (const float*)d_in[1];
  const float* Wb  = (const float*)d_in[2];
  const float* a1v = (const float*)d_in[3];
  const float* a2v = (const float*)d_in[4];
  const float* ab  = (const float*)d_in[5];
  const int*   adj = (const int*)d_in[6];
  float* out = (float*)d_out;

  unsigned short* wf   = (unsigned short*)d_ws;
  unsigned int*   adjp = (unsigned int*)((char*)d_ws + 36864);
  float*          wa1  = (float*)((char*)d_ws + 38912);
  float*          wa2  = (float*)((char*)d_ws + 39424);
  float*          ba   = (float*)((char*)d_ws + 39936);

  hipLaunchKernelGGL(prep1, dim3(1), dim3(256), 0, stream, Ww, Wb, a1v, a2v, wa1, wa2, ba);
  hipLaunchKernelGGL(prep2, dim3(72), dim3(256), 0, stream, Ww, adj, wa1, wa2, wf, adjp);

  const int BS = in_sizes[0] / 16384;  // 1024
  hipLaunchKernelGGL(gat_mfma, dim3(BS), dim3(256), 0, stream,
                     h, Wb, ab, wf, adjp, ba, out);
}